// Round 3
// baseline (372.126 us; speedup 1.0000x reference)
//
#include <hip/hip_runtime.h>
#include <hip/hip_bf16.h>

#define TT 50
#define BB 64
#define SS 100
#define HH 512
#define VT 32000
#define VE 5000
#define LDC 37000          // VT + VE
#define MROWS 3200         // T*B
#define NTILE 250          // VT/128
#define TSTR 136           // padded LDS tile stride (ushorts)
#define STG_COLS 22016     // bf16 cols staged in norm (clobber zone < 22000)

typedef __bf16 bf16x8 __attribute__((ext_vector_type(8)));
typedef float f32x4 __attribute__((ext_vector_type(4)));

__device__ __forceinline__ ushort f2bf(float f) {
    unsigned u = __float_as_uint(f);
    u += 0x7fffu + ((u >> 16) & 1u);   // RNE
    return (ushort)(u >> 16);
}
__device__ __forceinline__ float bflo(unsigned u) { return __uint_as_float(u << 16); }
__device__ __forceinline__ float bfhi(unsigned u) { return __uint_as_float(u & 0xffff0000u); }

// ---------------- pass 0: fp32 -> bf16 conversion of W and hidden ----------------
__global__ void convert_kernel(const float* __restrict__ W, const float* __restrict__ hid,
                               ushort* __restrict__ wsB, ushort* __restrict__ wsA) {
    int g = blockIdx.x * 256 + threadIdx.x;
    const int WG = 4096000;                      // W float4-groups
    float4 v;
    ushort* dst;
    if (g < WG) {
        v = ((const float4*)W)[g];
        dst = wsB + 4 * (size_t)g;
    } else {
        int h = g - WG;
        v = ((const float4*)hid)[h];
        dst = wsA + 4 * (size_t)h;
    }
    ushort4 o;
    o.x = f2bf(v.x); o.y = f2bf(v.y); o.z = f2bf(v.z); o.w = f2bf(v.w);
    *(ushort4*)dst = o;
}

// ---------------- pass 1: bf16 MFMA GEMM, BK=64, swizzled LDS ----------------
// C = A[3200x512] * B^T[32000x512] + bias.  128x128 tile, BK=64, 4 waves (2x2), 4x4 frags.
// LDS layout per matrix: [128 rows][128 bytes], byte ^= ((row&7)<<4) swizzle, achieved by
// inverse-swizzling the global source chunk (gload_lds dest stays linear) and XOR'ing reads.
__global__ void gemm_kernel(const ushort* __restrict__ A, const ushort* __restrict__ B,
                            const float* __restrict__ bias, ushort* __restrict__ outu,
                            float* __restrict__ pm, float* __restrict__ ps) {
    __shared__ char smem[34816];                 // staging A[0,16384) B[16384,32768) U tileT
    const int tid  = threadIdx.x;
    const int w    = tid >> 6;
    const int lane = tid & 63;
    const int wr   = w >> 1, wc = w & 1;
    const int brow = blockIdx.y * 128;
    const int bcol = blockIdx.x * 128;
    const int lr   = lane & 15;
    const int kg   = lane >> 4;

    char* ldsAb = smem;
    char* ldsBb = smem + 16384;
    ushort* tileT = (ushort*)smem;

    f32x4 acc[4][4];
#pragma unroll
    for (int m = 0; m < 4; ++m)
#pragma unroll
        for (int n = 0; n < 4; ++n)
            acc[m][n] = (f32x4){0.f, 0.f, 0.f, 0.f};

    for (int kt = 0; kt < 8; ++kt) {             // 8 K-steps of 64
        __syncthreads();                         // prev reads done before overwrite
#pragma unroll
        for (int j = 0; j < 4; ++j) {
            int c = tid + j * 256;               // chunk id 0..1023 (16B chunks)
            int row = c >> 3, kc = c & 7;
            int kcs = kc ^ (row & 7);            // inverse swizzle on SOURCE
            const ushort* srcA = A + (size_t)(brow + row) * HH + kt * 64 + kcs * 8;
            __builtin_amdgcn_global_load_lds(
                (const __attribute__((address_space(1))) void*)srcA,
                (__attribute__((address_space(3))) void*)(ldsAb + c * 16),
                16, 0, 0);
            const ushort* srcB = B + (size_t)(bcol + row) * HH + kt * 64 + kcs * 8;
            __builtin_amdgcn_global_load_lds(
                (const __attribute__((address_space(1))) void*)srcB,
                (__attribute__((address_space(3))) void*)(ldsBb + c * 16),
                16, 0, 0);
        }
        __syncthreads();                         // drain + all staged

#pragma unroll
        for (int s = 0; s < 2; ++s) {            // two K=32 sub-steps
            bf16x8 af[4], bfr[4];
            int xof = ((s * 4 + kg) ^ (lr & 7)) << 4;   // swizzled in-row byte offset
#pragma unroll
            for (int m = 0; m < 4; ++m)
                af[m] = *(const bf16x8*)(ldsAb + (wr * 64 + m * 16 + lr) * 128 + xof);
#pragma unroll
            for (int n = 0; n < 4; ++n)
                bfr[n] = *(const bf16x8*)(ldsBb + (wc * 64 + n * 16 + lr) * 128 + xof);
#pragma unroll
            for (int m = 0; m < 4; ++m)
#pragma unroll
                for (int n = 0; n < 4; ++n)
                    acc[m][n] = __builtin_amdgcn_mfma_f32_16x16x32_bf16(af[m], bfr[n], acc[m][n], 0, 0, 0);
        }
    }
    __syncthreads();                             // all LDS reads done before tileT reuse

    // ---- epilogue: acc (+bias) -> bf16 LDS tile ----
#pragma unroll
    for (int n = 0; n < 4; ++n) {
        int col = wc * 64 + n * 16 + lr;
        float bv = bias[bcol + col];
#pragma unroll
        for (int m = 0; m < 4; ++m) {
            int row0 = wr * 64 + m * 16 + kg * 4;
#pragma unroll
            for (int r = 0; r < 4; ++r)
                tileT[(row0 + r) * TSTR + col] = f2bf(acc[m][n][r] + bv);
        }
    }
    __syncthreads();

    // ---- coalesced bf16 store to out-row tails (256B segments) ----
#pragma unroll
    for (int it = 0; it < 8; ++it) {
        int idx = it * 256 + tid;
        int row = idx >> 4, ch = idx & 15;
        uint4 v = *(const uint4*)(&tileT[row * TSTR + ch * 8]);
        *(uint4*)(outu + (size_t)(brow + row) * 74000 + 42000 + bcol + ch * 8) = v;
    }

    // ---- per-row partial (max, sumexp) over this tile's 128 cols ----
    {
        int prow = tid >> 1, half = tid & 1;
        const ushort* trow = &tileT[prow * TSTR + half * 64];
        uint4 vv[8];
#pragma unroll
        for (int i = 0; i < 8; ++i) vv[i] = *(const uint4*)(trow + i * 8);
        float mx = -1e30f;
#pragma unroll
        for (int i = 0; i < 8; ++i) {
            mx = fmaxf(mx, fmaxf(fmaxf(bflo(vv[i].x), bfhi(vv[i].x)), fmaxf(bflo(vv[i].y), bfhi(vv[i].y))));
            mx = fmaxf(mx, fmaxf(fmaxf(bflo(vv[i].z), bfhi(vv[i].z)), fmaxf(bflo(vv[i].w), bfhi(vv[i].w))));
        }
        float sx = 0.f;
#pragma unroll
        for (int i = 0; i < 8; ++i) {
            sx += __expf(bflo(vv[i].x) - mx) + __expf(bfhi(vv[i].x) - mx)
                + __expf(bflo(vv[i].y) - mx) + __expf(bfhi(vv[i].y) - mx)
                + __expf(bflo(vv[i].z) - mx) + __expf(bfhi(vv[i].z) - mx)
                + __expf(bflo(vv[i].w) - mx) + __expf(bfhi(vv[i].w) - mx);
        }
        float om = __shfl_xor(mx, 1), os = __shfl_xor(sx, 1);
        float M = fmaxf(mx, om);
        float S = sx * __expf(mx - M) + os * __expf(om - M);
        if (half == 0) {
            pm[(size_t)blockIdx.x * MROWS + brow + prow] = M;
            ps[(size_t)blockIdx.x * MROWS + brow + prow] = S;
        }
    }
}

// ---------------- pass 2 (fused): lse reduce + normalize + gate + ext scatter + log ----
// One block (512 thr) per row. Stages only the bf16 cols that the fp32 write front can
// clobber (cols < 22016, bytes [84000,128032)); streams the rest straight from global.
__global__ __launch_bounds__(512) void norm_ext_kernel(float* __restrict__ out,
                                                       const float* __restrict__ pm,
                                                       const float* __restrict__ ps,
                                                       const float* __restrict__ dec,
                                                       const float* __restrict__ wc,
                                                       const float* __restrict__ bcp,
                                                       const float* __restrict__ attn,
                                                       const int* __restrict__ cte) {
    const int r = blockIdx.x;
    const int t = threadIdx.x;
    __shared__ float sm[8], ssum[8];
    __shared__ float lse_sh, csh;
    __shared__ ushort stg[STG_COLS];             // 44032 B
    __shared__ float bins[VE];                   // 20000 B

    // lse partials
    float m = -1e30f, s = 0.f;
    if (t < NTILE) {
        m = pm[(size_t)t * MROWS + r];
        s = ps[(size_t)t * MROWS + r];
    }
    for (int off = 1; off < 64; off <<= 1) {
        float om = __shfl_xor(m, off), os = __shfl_xor(s, off);
        float nm = fmaxf(m, om);
        s = s * __expf(m - nm) + os * __expf(om - nm);
        m = nm;
    }
    int w = t >> 6, lane = t & 63;
    if (lane == 0) { sm[w] = m; ssum[w] = s; }

    // gate partial: dot(dec[r], Wc) over 512 elems, 1/thread
    {
        float part = dec[(size_t)r * HH + t] * wc[t];
        for (int off = 1; off < 64; off <<= 1) part += __shfl_xor(part, off);
        if (lane == 0) ssum[w] += 0.f, sm[w] += 0.f;   // no-op keep
        __shared__ float red[8];
        if (lane == 0) red[w] = part;
        // red consumed below at t==0 (after barrier)
        if (t == 0) csh = 0.f;                          // init (overwritten after barrier)
        // stage bf16 clobber-zone cols into LDS
        const uint4* src = (const uint4*)((const ushort*)out + (size_t)r * 74000 + 42000);
        uint4* dstl = (uint4*)stg;
        for (int i = t; i < STG_COLS / 8; i += 512) dstl[i] = src[i];
        for (int v = t; v < VE; v += 512) bins[v] = 0.f;
        __syncthreads();
        if (t == 0) {
            float M = sm[0], S = ssum[0];
            for (int i = 1; i < 8; ++i) {
                float nm = fmaxf(M, sm[i]);
                S = S * __expf(M - nm) + ssum[i] * __expf(sm[i] - nm);
                M = nm;
            }
            lse_sh = M + __logf(S);
            float g = red[0] + red[1] + red[2] + red[3]
                    + red[4] + red[5] + red[6] + red[7] + bcp[0];
            csh = 1.f / (1.f + __expf(-g));
        }
    }
    __syncthreads();
    const float l = lse_sh;

    // normalize: bf16 -> fp32 log-softmax
    const uint4* gsrc = (const uint4*)((const ushort*)out + (size_t)r * 74000 + 42000);
    const uint4* lsrc = (const uint4*)stg;
    float4* orow = (float4*)(out + (size_t)r * LDC);
    for (int i = t; i < VT / 8; i += 512) {
        uint4 v = (i < STG_COLS / 8) ? lsrc[i] : gsrc[i];
        float4 a, b;
        a.x = bflo(v.x) - l; a.y = bfhi(v.x) - l;
        a.z = bflo(v.y) - l; a.w = bfhi(v.y) - l;
        b.x = bflo(v.z) - l; b.y = bfhi(v.z) - l;
        b.z = bflo(v.w) - l; b.w = bfhi(v.w) - l;
        orow[2 * i]     = a;
        orow[2 * i + 1] = b;
    }

    // ext scatter
    if (t < SS) {
        float aw = attn[(size_t)r * SS + t] * (1.f - csh);
        int idx = cte[t * BB + (r & 63)];
        if (idx != 0) atomicAdd(&bins[idx], aw);
    }
    __syncthreads();

    float4* eo = (float4*)(out + (size_t)r * LDC + VT);
    for (int v = t; v < VE / 4; v += 512) {
        float4 x;
        x.x = __logf(fminf(fmaxf(bins[4 * v + 0], 0.001f), 0.999f));
        x.y = __logf(fminf(fmaxf(bins[4 * v + 1], 0.001f), 0.999f));
        x.z = __logf(fminf(fmaxf(bins[4 * v + 2], 0.001f), 0.999f));
        x.w = __logf(fminf(fmaxf(bins[4 * v + 3], 0.001f), 0.999f));
        eo[v] = x;
    }
}

extern "C" void kernel_launch(void* const* d_in, const int* in_sizes, int n_in,
                              void* d_out, int out_size, void* d_ws, size_t ws_size,
                              hipStream_t stream) {
    const float* hidden = (const float*)d_in[0];
    const float* dec    = (const float*)d_in[1];
    // d_in[2] = concat_c, unused by the reference
    const float* attn   = (const float*)d_in[3];
    const int*   cte    = (const int*)d_in[4];
    const float* W      = (const float*)d_in[5];
    const float* bias   = (const float*)d_in[6];
    const float* Wc     = (const float*)d_in[7];
    const float* bc     = (const float*)d_in[8];
    float* out = (float*)d_out;

    ushort* wsB = (ushort*)d_ws;                       // W bf16  [32000][512]  32.77 MB
    ushort* wsA = wsB + (size_t)VT * HH;               // hidden bf16 [3200][512] 3.28 MB
    float*  pm  = (float*)(wsA + (size_t)MROWS * HH);  // partial max [250][3200] 3.2 MB
    float*  ps  = pm + (size_t)NTILE * MROWS;          // partial sum [250][3200] 3.2 MB

    convert_kernel<<<17600, 256, 0, stream>>>(W, hidden, wsB, wsA);
    gemm_kernel<<<dim3(NTILE, 25), 256, 0, stream>>>(wsA, wsB, bias, (ushort*)out, pm, ps);
    norm_ext_kernel<<<MROWS, 512, 0, stream>>>(out, pm, ps, dec, Wc, bc, attn, cte);
}

// Round 4
// 349.570 us; speedup vs baseline: 1.0645x; 1.0645x over previous
//
#include <hip/hip_runtime.h>
#include <hip/hip_bf16.h>

#define TT 50
#define BB 64
#define SS 100
#define HH 512
#define VT 32000
#define VE 5000
#define LDC 37000          // VT + VE
#define MROWS 3200         // T*B
#define NTILE 250          // VT/128
#define TSTR 136           // padded LDS tile stride (ushorts)

typedef __bf16 bf16x8 __attribute__((ext_vector_type(8)));
typedef float f32x4 __attribute__((ext_vector_type(4)));

__device__ __forceinline__ ushort f2bf(float f) {
    unsigned u = __float_as_uint(f);
    u += 0x7fffu + ((u >> 16) & 1u);   // RNE
    return (ushort)(u >> 16);
}
__device__ __forceinline__ float bflo(unsigned u) { return __uint_as_float(u << 16); }
__device__ __forceinline__ float bfhi(unsigned u) { return __uint_as_float(u & 0xffff0000u); }

// ---------------- pass 0: fp32 -> bf16 conversion of W and hidden ----------------
__global__ void convert_kernel(const float* __restrict__ W, const float* __restrict__ hid,
                               ushort* __restrict__ wsB, ushort* __restrict__ wsA) {
    int g = blockIdx.x * 256 + threadIdx.x;
    const int WG = 4096000;                      // W float4-groups
    float4 v;
    ushort* dst;
    if (g < WG) {
        v = ((const float4*)W)[g];
        dst = wsB + 4 * (size_t)g;
    } else {
        int h = g - WG;
        v = ((const float4*)hid)[h];
        dst = wsA + 4 * (size_t)h;
    }
    ushort4 o;
    o.x = f2bf(v.x); o.y = f2bf(v.y); o.z = f2bf(v.z); o.w = f2bf(v.w);
    *(ushort4*)dst = o;
}

// ---------------- pass 1: bf16 MFMA GEMM, BK=32, double-buffered 2-phase ----------------
// C = A[3200x512] * B^T[32000x512] + bias.  128x128 tile, 4 waves (2x2), 4x4 frags.
// Schedule per K-step: STAGE(next buf) -> vmcnt(4) [cur's 4 loads done, next's 4 in
// flight across the barrier] -> s_barrier -> ds_read+MFMA(cur) -> s_barrier.
__global__ __launch_bounds__(256) void gemm_kernel(const ushort* __restrict__ A,
                                                   const ushort* __restrict__ B,
                                                   const float* __restrict__ bias,
                                                   ushort* __restrict__ outu,
                                                   float* __restrict__ pm,
                                                   float* __restrict__ ps) {
    __shared__ char smem[34816];                 // dbuf staging 32 KB  U  tileT 34.8 KB
    const int tid  = threadIdx.x;
    const int w    = tid >> 6;
    const int lane = tid & 63;
    const int wr   = w >> 1, wc = w & 1;
    const int brow = blockIdx.y * 128;
    const int bcol = blockIdx.x * 128;
    const int lr   = lane & 15;
    const int kg   = lane >> 4;

    ushort* tileT = (ushort*)smem;
    // staging chunk for this thread: 2 chunks per matrix per K-step
    const int c0 = tid, c1 = tid + 256;          // chunk ids in [0,512)
    const int r0 = c0 >> 2, k0 = c0 & 3;
    const int r1 = c1 >> 2, k1 = c1 & 3;

    f32x4 acc[4][4];
#pragma unroll
    for (int m = 0; m < 4; ++m)
#pragma unroll
        for (int n = 0; n < 4; ++n)
            acc[m][n] = (f32x4){0.f, 0.f, 0.f, 0.f};

    // STAGE(buf, kt): 4 global_load_lds (A c0, A c1, B c0, B c1)
#define STAGE(buf, kt)                                                                      \
    do {                                                                                    \
        char* bA = smem + (buf) * 8192;                                                     \
        char* bB = smem + 16384 + (buf) * 8192;                                             \
        __builtin_amdgcn_global_load_lds(                                                   \
            (const __attribute__((address_space(1))) void*)(A + (size_t)(brow + r0) * HH + (kt) * 32 + k0 * 8), \
            (__attribute__((address_space(3))) void*)(bA + c0 * 16), 16, 0, 0);             \
        __builtin_amdgcn_global_load_lds(                                                   \
            (const __attribute__((address_space(1))) void*)(A + (size_t)(brow + r1) * HH + (kt) * 32 + k1 * 8), \
            (__attribute__((address_space(3))) void*)(bA + c1 * 16), 16, 0, 0);             \
        __builtin_amdgcn_global_load_lds(                                                   \
            (const __attribute__((address_space(1))) void*)(B + (size_t)(bcol + r0) * HH + (kt) * 32 + k0 * 8), \
            (__attribute__((address_space(3))) void*)(bB + c0 * 16), 16, 0, 0);             \
        __builtin_amdgcn_global_load_lds(                                                   \
            (const __attribute__((address_space(1))) void*)(B + (size_t)(bcol + r1) * HH + (kt) * 32 + k1 * 8), \
            (__attribute__((address_space(3))) void*)(bB + c1 * 16), 16, 0, 0);             \
    } while (0)

    STAGE(0, 0);                                 // prologue
    for (int kt = 0; kt < 16; ++kt) {
        const int cur = kt & 1;
        if (kt < 15) {
            STAGE(cur ^ 1, kt + 1);              // issue next tile's loads first
            asm volatile("s_waitcnt vmcnt(4)" ::: "memory");   // cur's 4 done
        } else {
            asm volatile("s_waitcnt vmcnt(0)" ::: "memory");
        }
        __builtin_amdgcn_sched_barrier(0);
        __builtin_amdgcn_s_barrier();            // all waves: cur buffer ready
        __builtin_amdgcn_sched_barrier(0);

        const char* pa = smem + cur * 8192;
        const char* pb = smem + 16384 + cur * 8192;
        bf16x8 af[4], bfr[4];
#pragma unroll
        for (int m = 0; m < 4; ++m)
            af[m] = *(const bf16x8*)(pa + (wr * 64 + m * 16 + lr) * 64 + kg * 16);
#pragma unroll
        for (int n = 0; n < 4; ++n)
            bfr[n] = *(const bf16x8*)(pb + (wc * 64 + n * 16 + lr) * 64 + kg * 16);
#pragma unroll
        for (int m = 0; m < 4; ++m)
#pragma unroll
            for (int n = 0; n < 4; ++n)
                acc[m][n] = __builtin_amdgcn_mfma_f32_16x16x32_bf16(af[m], bfr[n], acc[m][n], 0, 0, 0);

        __builtin_amdgcn_sched_barrier(0);
        __builtin_amdgcn_s_barrier();            // all waves done reading cur
    }
#undef STAGE
    __syncthreads();                             // fence before tileT reuse of smem

    // ---- epilogue: acc (+bias) -> bf16 LDS tile ----
#pragma unroll
    for (int n = 0; n < 4; ++n) {
        int col = wc * 64 + n * 16 + lr;
        float bv = bias[bcol + col];
#pragma unroll
        for (int m = 0; m < 4; ++m) {
            int row0 = wr * 64 + m * 16 + kg * 4;
#pragma unroll
            for (int r = 0; r < 4; ++r)
                tileT[(row0 + r) * TSTR + col] = f2bf(acc[m][n][r] + bv);
        }
    }
    __syncthreads();

    // ---- coalesced bf16 store to out-row tails (256B segments) ----
#pragma unroll
    for (int it = 0; it < 8; ++it) {
        int idx = it * 256 + tid;
        int row = idx >> 4, ch = idx & 15;
        uint4 v = *(const uint4*)(&tileT[row * TSTR + ch * 8]);
        *(uint4*)(outu + (size_t)(brow + row) * 74000 + 42000 + bcol + ch * 8) = v;
    }

    // ---- per-row partial (max, sumexp) over this tile's 128 cols ----
    {
        int prow = tid >> 1, half = tid & 1;
        const ushort* trow = &tileT[prow * TSTR + half * 64];
        uint4 vv[8];
#pragma unroll
        for (int i = 0; i < 8; ++i) vv[i] = *(const uint4*)(trow + i * 8);
        float mx = -1e30f;
#pragma unroll
        for (int i = 0; i < 8; ++i) {
            mx = fmaxf(mx, fmaxf(fmaxf(bflo(vv[i].x), bfhi(vv[i].x)), fmaxf(bflo(vv[i].y), bfhi(vv[i].y))));
            mx = fmaxf(mx, fmaxf(fmaxf(bflo(vv[i].z), bfhi(vv[i].z)), fmaxf(bflo(vv[i].w), bfhi(vv[i].w))));
        }
        float sx = 0.f;
#pragma unroll
        for (int i = 0; i < 8; ++i) {
            sx += __expf(bflo(vv[i].x) - mx) + __expf(bfhi(vv[i].x) - mx)
                + __expf(bflo(vv[i].y) - mx) + __expf(bfhi(vv[i].y) - mx)
                + __expf(bflo(vv[i].z) - mx) + __expf(bfhi(vv[i].z) - mx)
                + __expf(bflo(vv[i].w) - mx) + __expf(bfhi(vv[i].w) - mx);
        }
        float om = __shfl_xor(mx, 1), os = __shfl_xor(sx, 1);
        float M = fmaxf(mx, om);
        float S = sx * __expf(mx - M) + os * __expf(om - M);
        if (half == 0) {
            pm[(size_t)blockIdx.x * MROWS + brow + prow] = M;
            ps[(size_t)blockIdx.x * MROWS + brow + prow] = S;
        }
    }
}

// ---------------- pass 2 (fused): lse reduce + gate + scatter + in-place normalize ----
// One block (256 thr) per row. No LDS staging of the bf16 row: the in-place sweep is
// provably safe — fp32 write of uint4-index iw clobbers bf16 index ir only if
// ir < 2*iw - 5248; with barriers every 2 iterations (skew <= 512 indices) the clobber
// front never catches the read front (needs 256n > 4226, loop max n=15).
__global__ __launch_bounds__(256) void norm_ext_kernel(float* __restrict__ out,
                                                       const float* __restrict__ pm,
                                                       const float* __restrict__ ps,
                                                       const float* __restrict__ dec,
                                                       const float* __restrict__ wc,
                                                       const float* __restrict__ bcp,
                                                       const float* __restrict__ attn,
                                                       const int* __restrict__ cte) {
    const int r = blockIdx.x;
    const int t = threadIdx.x;
    const int w = t >> 6, lane = t & 63;
    __shared__ float sm[4], ssv[4], red[4];
    __shared__ float lse_sh, csh;
    __shared__ float bins[VE];                   // 20000 B

    // lse partials (250 of them)
    float m = -1e30f, s = 0.f;
    if (t < NTILE) {
        m = pm[(size_t)t * MROWS + r];
        s = ps[(size_t)t * MROWS + r];
    }
    for (int off = 1; off < 64; off <<= 1) {
        float om = __shfl_xor(m, off), os = __shfl_xor(s, off);
        float nm = fmaxf(m, om);
        s = s * __expf(m - nm) + os * __expf(om - nm);
        m = nm;
    }
    if (lane == 0) { sm[w] = m; ssv[w] = s; }

    // gate partial: dot(dec[r], Wc), 2 elems/thread
    {
        float part = dec[(size_t)r * HH + t] * wc[t]
                   + dec[(size_t)r * HH + t + 256] * wc[t + 256];
        for (int off = 1; off < 64; off <<= 1) part += __shfl_xor(part, off);
        if (lane == 0) red[w] = part;
    }
    for (int v = t; v < VE; v += 256) bins[v] = 0.f;
    __syncthreads();

    if (t == 0) {
        float M = sm[0], S = ssv[0];
        for (int i = 1; i < 4; ++i) {
            float nm = fmaxf(M, sm[i]);
            S = S * __expf(M - nm) + ssv[i] * __expf(sm[i] - nm);
            M = nm;
        }
        lse_sh = M + __logf(S);
        float g = red[0] + red[1] + red[2] + red[3] + bcp[0];
        csh = 1.f / (1.f + __expf(-g));
    }
    __syncthreads();
    const float l = lse_sh;
    const float c = csh;

    // ext scatter into LDS bins (completes before the post-sweep barrier)
    if (t < SS) {
        float aw = attn[(size_t)r * SS + t] * (1.f - c);
        int idx = cte[t * BB + (r & 63)];
        if (idx != 0) atomicAdd(&bins[idx], aw);
    }

    // in-place normalize sweep: bf16 (row tail) -> fp32 log-softmax (row head)
    const uint4* gsrc = (const uint4*)((const ushort*)out + (size_t)r * 74000 + 42000);
    float4* orow = (float4*)(out + (size_t)r * LDC);
    for (int n = 0; n < 16; ++n) {
        int i = t + 256 * n;
        if (i < VT / 8) {
            uint4 v = gsrc[i];
            float4 a, b;
            a.x = bflo(v.x) - l; a.y = bfhi(v.x) - l;
            a.z = bflo(v.y) - l; a.w = bfhi(v.y) - l;
            b.x = bflo(v.z) - l; b.y = bfhi(v.z) - l;
            b.z = bflo(v.w) - l; b.w = bfhi(v.w) - l;
            orow[2 * i]     = a;
            orow[2 * i + 1] = b;
        }
        if ((n & 1) == 1) __syncthreads();       // bound the read/write skew
    }
    __syncthreads();                             // all bf16 reads + scatter done

    float4* eo = (float4*)(out + (size_t)r * LDC + VT);
    for (int v = t; v < VE / 4; v += 256) {
        float4 x;
        x.x = __logf(fminf(fmaxf(bins[4 * v + 0], 0.001f), 0.999f));
        x.y = __logf(fminf(fmaxf(bins[4 * v + 1], 0.001f), 0.999f));
        x.z = __logf(fminf(fmaxf(bins[4 * v + 2], 0.001f), 0.999f));
        x.w = __logf(fminf(fmaxf(bins[4 * v + 3], 0.001f), 0.999f));
        eo[v] = x;
    }
}

extern "C" void kernel_launch(void* const* d_in, const int* in_sizes, int n_in,
                              void* d_out, int out_size, void* d_ws, size_t ws_size,
                              hipStream_t stream) {
    const float* hidden = (const float*)d_in[0];
    const float* dec    = (const float*)d_in[1];
    // d_in[2] = concat_c, unused by the reference
    const float* attn   = (const float*)d_in[3];
    const int*   cte    = (const int*)d_in[4];
    const float* W      = (const float*)d_in[5];
    const float* bias   = (const float*)d_in[6];
    const float* Wc     = (const float*)d_in[7];
    const float* bc     = (const float*)d_in[8];
    float* out = (float*)d_out;

    ushort* wsB = (ushort*)d_ws;                       // W bf16  [32000][512]  32.77 MB
    ushort* wsA = wsB + (size_t)VT * HH;               // hidden bf16 [3200][512] 3.28 MB
    float*  pm  = (float*)(wsA + (size_t)MROWS * HH);  // partial max [250][3200] 3.2 MB
    float*  ps  = pm + (size_t)NTILE * MROWS;          // partial sum [250][3200] 3.2 MB

    convert_kernel<<<17600, 256, 0, stream>>>(W, hidden, wsB, wsA);
    gemm_kernel<<<dim3(NTILE, 25), 256, 0, stream>>>(wsA, wsB, bias, (ushort*)out, pm, ps);
    norm_ext_kernel<<<MROWS, 256, 0, stream>>>(out, pm, ps, dec, Wc, bc, attn, cte);
}